// Round 4
// baseline (341.610 us; speedup 1.0000x reference)
//
#include <hip/hip_runtime.h>
#include <math.h>

#define N_TOK 8192
#define C_DIM 128
#define NHD   8
#define HDIM  16
#define NR    1024
#define EPSV  1e-5f
#define QK_SCALE 0.25f

typedef __attribute__((ext_vector_type(8))) short short8;
typedef __attribute__((ext_vector_type(4))) float f32x4;

__device__ __forceinline__ float gelu_f(float v) {
    return 0.5f * v * (1.0f + erff(v * 0.70710678118654752f));
}
__device__ __forceinline__ float uaf(unsigned int u) {
    union { unsigned int u; float f; } x; x.u = u; return x.f;
}
__device__ __forceinline__ short f2b(float v) {
    union { float f; unsigned int u; } x; x.f = v;
    unsigned int r = x.u + 0x7fffu + ((x.u >> 16) & 1u);
    return (short)(r >> 16);
}
// load 16 bf16 (32B, 16B-aligned) -> 16 floats
__device__ __forceinline__ void ld16bf(const short* p, float* d) {
    uint4 a = *(const uint4*)p;
    uint4 b = *(const uint4*)(p + 8);
    d[0]  = uaf(a.x << 16); d[1]  = uaf(a.x & 0xffff0000u);
    d[2]  = uaf(a.y << 16); d[3]  = uaf(a.y & 0xffff0000u);
    d[4]  = uaf(a.z << 16); d[5]  = uaf(a.z & 0xffff0000u);
    d[6]  = uaf(a.w << 16); d[7]  = uaf(a.w & 0xffff0000u);
    d[8]  = uaf(b.x << 16); d[9]  = uaf(b.x & 0xffff0000u);
    d[10] = uaf(b.y << 16); d[11] = uaf(b.y & 0xffff0000u);
    d[12] = uaf(b.z << 16); d[13] = uaf(b.z & 0xffff0000u);
    d[14] = uaf(b.w << 16); d[15] = uaf(b.w & 0xffff0000u);
}

// ---------------- weight fp32 -> bf16 conversion ----------------
struct CvtDesc { const float* src; short* dst; int n; int pad; };
struct CvtArgs { CvtDesc d[10]; };
__global__ __launch_bounds__(256) void cvtw_k(CvtArgs a) {
    CvtDesc dd = a.d[blockIdx.y];
    for (int i = blockIdx.x * 256 + threadIdx.x; i < dd.n; i += gridDim.x * 256)
        dd.dst[i] = f2b(dd.src[i]);
}

// ---------------- transpose x (C,N) -> xt (N,C) f32 ----------------
__global__ __launch_bounds__(256) void transpose_k(const float* __restrict__ x,
                                                   float* __restrict__ xt) {
    __shared__ float tile[32][33];
    int n0 = blockIdx.x * 32, c0 = blockIdx.y * 32;
    int tx = threadIdx.x, ty = threadIdx.y;
#pragma unroll
    for (int k = 0; k < 4; ++k)
        tile[ty + k * 8][tx] = x[(size_t)(c0 + ty + k * 8) * N_TOK + n0 + tx];
    __syncthreads();
#pragma unroll
    for (int k = 0; k < 4; ++k)
        xt[(size_t)(n0 + ty + k * 8) * C_DIM + c0 + tx] = tile[tx][ty + k * 8];
}

// ---------------- first LN: fp32 in, two bf16 outputs (local & global gammas) -------
__global__ __launch_bounds__(256) void ln_token_k(const float* __restrict__ in,
                                                  const float* __restrict__ g1, const float* __restrict__ b1,
                                                  short* __restrict__ o1,
                                                  const float* __restrict__ g2, const float* __restrict__ b2,
                                                  short* __restrict__ o2) {
    int lane = threadIdx.x & 63;
    int n = blockIdx.x * 4 + (threadIdx.x >> 6);
    float v0 = in[(size_t)n * C_DIM + lane];
    float v1 = in[(size_t)n * C_DIM + 64 + lane];
    float s = v0 + v1, sq = v0 * v0 + v1 * v1;
#pragma unroll
    for (int off = 32; off >= 1; off >>= 1) {
        s += __shfl_xor(s, off);
        sq += __shfl_xor(sq, off);
    }
    float m = s * (1.0f / 128.0f);
    float var = sq * (1.0f / 128.0f) - m * m;
    float rs = rsqrtf(var + EPSV);
    float h0 = (v0 - m) * rs, h1 = (v1 - m) * rs;
    o1[(size_t)n * C_DIM + lane]      = f2b(h0 * g1[lane] + b1[lane]);
    o1[(size_t)n * C_DIM + 64 + lane] = f2b(h1 * g1[lane + 64] + b1[lane + 64]);
    o2[(size_t)n * C_DIM + lane]      = f2b(h0 * g2[lane] + b2[lane]);
    o2[(size_t)n * C_DIM + 64 + lane] = f2b(h1 * g2[lane + 64] + b2[lane + 64]);
}

// ---------------- second LN, paired across branches (one launch) ----------------
__global__ __launch_bounds__(256) void ln2_pair_k(const float* __restrict__ in0,
                                                  const float* __restrict__ g0, const float* __restrict__ b0,
                                                  short* __restrict__ o0,
                                                  const float* __restrict__ in1,
                                                  const float* __restrict__ g1, const float* __restrict__ b1,
                                                  short* __restrict__ o1) {
    int blk = blockIdx.x;
    bool sel = blk >= 2048;
    blk &= 2047;
    const float* in = sel ? in1 : in0;
    const float* g  = sel ? g1 : g0;
    const float* b  = sel ? b1 : b0;
    short* o        = sel ? o1 : o0;
    int lane = threadIdx.x & 63;
    int n = blk * 4 + (threadIdx.x >> 6);
    float v0 = in[(size_t)n * C_DIM + lane];
    float v1 = in[(size_t)n * C_DIM + 64 + lane];
    float s = v0 + v1, sq = v0 * v0 + v1 * v1;
#pragma unroll
    for (int off = 32; off >= 1; off >>= 1) {
        s += __shfl_xor(s, off);
        sq += __shfl_xor(sq, off);
    }
    float m = s * (1.0f / 128.0f);
    float var = sq * (1.0f / 128.0f) - m * m;
    float rs = rsqrtf(var + EPSV);
    o[(size_t)n * C_DIM + lane]      = f2b((v0 - m) * rs * g[lane] + b[lane]);
    o[(size_t)n * C_DIM + 64 + lane] = f2b((v1 - m) * rs * g[lane + 64] + b[lane + 64]);
}

// ---------------- bf16 MFMA GEMM, branch-paired via blockIdx.z ----------------
// EPI: 0 -> bf16 out; 1 -> f32 out = acc+bias+res; 2 -> bf16 out = gelu(acc+bias)
//      3 -> f32 split-K partial (z>>2 selects conv, z&3 selects K slice)
struct MArgs {
    const short* A[2]; const short* W[2];
    const float* bias[2]; const float* res[2];
    void* out[2];
};
template <int EPI>
__global__ __launch_bounds__(256) void mgemm_k(MArgs ga, int M, int N, int K, int kslice) {
    int zi    = (EPI == 3) ? (blockIdx.z >> 2) : blockIdx.z;
    int slice = (EPI == 3) ? (blockIdx.z & 3) : 0;
    const short* A = ga.A[zi];
    const short* W = ga.W[zi];
    __shared__ short As[128 * 64];
    __shared__ short Bs[128 * 64];
    int t = threadIdx.x;
    int w = t >> 6, l = t & 63;
    int m0 = blockIdx.x * 128, n0 = blockIdx.y * 128;
    int wm = (w >> 1) * 64, wn = (w & 1) * 64;
    int kbeg = (EPI == 3) ? slice * kslice : 0;
    int kend = kbeg + ((EPI == 3) ? kslice : K);

    f32x4 acc[4][4];
#pragma unroll
    for (int a = 0; a < 4; ++a)
#pragma unroll
        for (int b = 0; b < 4; ++b) acc[a][b] = f32x4{0.f, 0.f, 0.f, 0.f};

    for (int k0 = kbeg; k0 < kend; k0 += 64) {
        __syncthreads();
#pragma unroll
        for (int c = 0; c < 4; ++c) {
            int chunk = c * 256 + t;
            int row = chunk >> 3;
            int slot = chunk & 7;
            int ss = slot ^ (row & 7);     // XOR swizzle (T2)
            uint4 av = *(const uint4*)(A + (size_t)(m0 + row) * K + k0 + slot * 8);
            *(uint4*)(As + row * 64 + ss * 8) = av;
            uint4 wv = *(const uint4*)(W + (size_t)(n0 + row) * K + k0 + slot * 8);
            *(uint4*)(Bs + row * 64 + ss * 8) = wv;
        }
        __syncthreads();
#pragma unroll
        for (int kk = 0; kk < 2; ++kk) {
            short8 af[4], bf[4];
            int sl = kk * 4 + (l >> 4);
#pragma unroll
            for (int mf = 0; mf < 4; ++mf) {
                int row = wm + mf * 16 + (l & 15);
                af[mf] = *(const short8*)(As + row * 64 + (sl ^ (row & 7)) * 8);
            }
#pragma unroll
            for (int nf = 0; nf < 4; ++nf) {
                int row = wn + nf * 16 + (l & 15);
                bf[nf] = *(const short8*)(Bs + row * 64 + (sl ^ (row & 7)) * 8);
            }
#pragma unroll
            for (int mf = 0; mf < 4; ++mf)
#pragma unroll
                for (int nf = 0; nf < 4; ++nf)
                    acc[mf][nf] = __builtin_amdgcn_mfma_f32_16x16x32_bf16(
                        af[mf], bf[nf], acc[mf][nf], 0, 0, 0);
        }
    }

    // C/D layout: col = lane&15, row = (lane>>4)*4 + reg
#pragma unroll
    for (int mf = 0; mf < 4; ++mf) {
#pragma unroll
        for (int nf = 0; nf < 4; ++nf) {
            int col = n0 + wn + nf * 16 + (l & 15);
#pragma unroll
            for (int j = 0; j < 4; ++j) {
                int row = m0 + wm + mf * 16 + (l >> 4) * 4 + j;
                float v = acc[mf][nf][j];
                if (EPI == 0) {
                    ((short*)ga.out[zi])[(size_t)row * N + col] = f2b(v);
                } else if (EPI == 1) {
                    v += ga.bias[zi][col] + ga.res[zi][(size_t)row * N + col];
                    ((float*)ga.out[zi])[(size_t)row * N + col] = v;
                } else if (EPI == 2) {
                    v = gelu_f(v + ga.bias[zi][col]);
                    ((short*)ga.out[zi])[(size_t)row * N + col] = f2b(v);
                } else {
                    ((float*)ga.out[zi])[(size_t)slice * M * N + (size_t)row * N + col] = v;
                }
            }
        }
    }
}

// ---------------- local patch attention, bf16 in/out ----------------
__global__ __launch_bounds__(256) void local_attn_k(const short* __restrict__ qkv,
                                                    short* __restrict__ ob) {
    __shared__ float ks[NHD][32][HDIM];
    __shared__ float vs[NHD][32][HDIM];
    int m = threadIdx.x, h = threadIdx.y, r = blockIdx.x;
    int zd = r >> 6, zh = (r >> 3) & 7, zw = r & 7;
    int pd = m >> 4, ph = (m >> 2) & 3, pw = m & 3;
    int n = (zd * 2 + pd) * 1024 + (zh * 4 + ph) * 32 + (zw * 4 + pw);
    const short* base = qkv + (size_t)n * 384 + h * HDIM;
    float q[16], kt[16], vt[16];
    ld16bf(base, q);
    ld16bf(base + 128, kt);
    ld16bf(base + 256, vt);
#pragma unroll
    for (int d = 0; d < 16; ++d) { ks[h][m][d] = kt[d]; vs[h][m][d] = vt[d]; }
    __syncthreads();
    float s[32];
#pragma unroll
    for (int j = 0; j < 32; ++j) {
        float d = 0.f;
#pragma unroll
        for (int dd = 0; dd < 16; ++dd) d += q[dd] * ks[h][j][dd];
        s[j] = __expf(d * QK_SCALE);   // bounded scores: exp-direct
    }
    float sum = 0.f;
#pragma unroll
    for (int j = 0; j < 32; ++j) sum += s[j];
    float inv = 1.0f / sum;
    float oo[16] = {};
#pragma unroll
    for (int j = 0; j < 32; ++j) {
        float p = s[j] * inv;
#pragma unroll
        for (int dd = 0; dd < 16; ++dd) oo[dd] += p * vs[h][j][dd];
    }
    // torch-faithful quirk: o (NH,Npl,HD) -> swap(-1,-2) -> reshape (Npl, C)
#pragma unroll
    for (int dd = 0; dd < 16; ++dd) {
        int n2 = h * 4 + (dd >> 2);
        int c2 = (dd & 3) * 32 + m;
        int pd2 = n2 >> 4, ph2 = (n2 >> 2) & 3, pw2 = n2 & 3;
        int nn = (zd * 2 + pd2) * 1024 + (zh * 4 + ph2) * 32 + (zw * 4 + pw2);
        ob[(size_t)nn * C_DIM + c2] = f2b(oo[dd]);
    }
}

// ---------------- gather reduced K/V conv inputs ----------------
__global__ __launch_bounds__(256) void gather_k(const short* __restrict__ qkv,
                                                short* __restrict__ kg, short* __restrict__ vg) {
    int idx = blockIdx.x * 256 + threadIdx.x;
    int nr = idx >> 10, qq = idx & 1023;
    int ci = qq >> 3, off = qq & 7;
    int od = off >> 2, oh = (off >> 1) & 1, ow = off & 1;
    int d2 = nr >> 8, h2 = (nr >> 4) & 15, w2 = nr & 15;
    int n = (2 * d2 + od) * 1024 + (2 * h2 + oh) * 32 + (2 * w2 + ow);
    kg[idx] = qkv[(size_t)n * 384 + 128 + ci];
    vg[idx] = qkv[(size_t)n * 384 + 256 + ci];
}

// ---------------- sum 4 split-K partials + per-head LN (K and V in one launch) ------
__global__ __launch_bounds__(256) void ln_head_sum_k(const float* __restrict__ kpart,
                                                     const float* __restrict__ vpart,
                                                     const float* __restrict__ gk, const float* __restrict__ bk,
                                                     const float* __restrict__ gv, const float* __restrict__ bv,
                                                     float* __restrict__ kout, float* __restrict__ vout) {
    int idx = blockIdx.x * 256 + threadIdx.x;   // 0..16383
    bool sel = idx >= 8192;
    int id2 = idx & 8191;
    const float* part = sel ? vpart : kpart;
    const float* g    = sel ? gv : gk;
    const float* b    = sel ? bv : bk;
    float* outb       = sel ? vout : kout;
    int nr = id2 >> 3, h = id2 & 7;
    size_t base = (size_t)nr * C_DIM + h * HDIM;
    float v[16] = {};
#pragma unroll
    for (int p = 0; p < 4; ++p) {
        const float* pp = part + (size_t)p * (NR * C_DIM) + base;
#pragma unroll
        for (int d4 = 0; d4 < 4; ++d4) {
            float4 t = *(const float4*)(pp + d4 * 4);
            v[d4 * 4 + 0] += t.x; v[d4 * 4 + 1] += t.y;
            v[d4 * 4 + 2] += t.z; v[d4 * 4 + 3] += t.w;
        }
    }
    float s = 0.f;
#pragma unroll
    for (int i = 0; i < 16; ++i) s += v[i];
    float m = s * (1.0f / 16.0f);
    float sq = 0.f;
#pragma unroll
    for (int i = 0; i < 16; ++i) { float d = v[i] - m; sq += d * d; }
    float rs = rsqrtf(sq * (1.0f / 16.0f) + EPSV);
    float* op = outb + (size_t)h * (NR * HDIM) + (size_t)nr * HDIM;
#pragma unroll
    for (int i = 0; i < 16; ++i) op[i] = (v[i] - m) * rs * g[i] + b[i];
}

// ---------------- global attention v4: spill-free, no LDS, no barriers ----------------
// grid (512, 8); block 256 = 8 groups of 32 lanes; 2 queries/group-thread pair.
__global__ __launch_bounds__(256) void gattn_k(const short* __restrict__ qkv,
                                               const float* __restrict__ kr,  // [8][1024][16]
                                               const float* __restrict__ vr,
                                               short* __restrict__ ob) {
    int t = threadIdx.x;
    int h = blockIdx.y;
    int g = t >> 5, i = t & 31;
    int q0 = blockIdx.x * 16 + g * 2;

    float qa[16], qb[16];
    ld16bf(qkv + (size_t)q0 * 384 + h * HDIM, qa);
    ld16bf(qkv + (size_t)(q0 + 1) * 384 + h * HDIM, qb);
#pragma unroll
    for (int d = 0; d < 16; ++d) { qa[d] *= QK_SCALE; qb[d] *= QK_SCALE; }

    const float* kh = kr + (size_t)h * (NR * HDIM);
    const float* vh = vr + (size_t)h * (NR * HDIM);

    float sma = 0.f, smb = 0.f;
    float oa[16] = {}, obv[16] = {};
#pragma unroll 1
    for (int j = i; j < NR; j += 32) {
        float kv[16];
#pragma unroll
        for (int d4 = 0; d4 < 4; ++d4)
            *(float4*)&kv[d4 * 4] = *(const float4*)(kh + j * HDIM + d4 * 4);
        float sa = 0.f, sb = 0.f;
#pragma unroll
        for (int d = 0; d < 16; ++d) { sa += qa[d] * kv[d]; sb += qb[d] * kv[d]; }
        float pa = __expf(sa), pb = __expf(sb);
        sma += pa; smb += pb;
        float vv[16];
#pragma unroll
        for (int d4 = 0; d4 < 4; ++d4)
            *(float4*)&vv[d4 * 4] = *(const float4*)(vh + j * HDIM + d4 * 4);
#pragma unroll
        for (int d = 0; d < 16; ++d) { oa[d] += pa * vv[d]; obv[d] += pb * vv[d]; }
    }
    // butterfly reduce across the 32-lane group
#pragma unroll
    for (int off = 16; off >= 1; off >>= 1) {
        sma += __shfl_xor(sma, off);
        smb += __shfl_xor(smb, off);
    }
#pragma unroll
    for (int d = 0; d < 16; ++d) {
        float va = oa[d], vb = obv[d];
#pragma unroll
        for (int off = 16; off >= 1; off >>= 1) {
            va += __shfl_xor(va, off);
            vb += __shfl_xor(vb, off);
        }
        oa[d] = va; obv[d] = vb;
    }
    if (i < 16) {
        ob[(size_t)q0 * C_DIM + h * HDIM + i]       = f2b(oa[i] / sma);
        ob[(size_t)(q0 + 1) * C_DIM + h * HDIM + i] = f2b(obv[i] / smb);
    }
}

// ---------------- final gate: out(C,N) = x * sigmoid(loc + glo) ----------------
__global__ __launch_bounds__(256) void gate_k(const float* __restrict__ x,
                                              const float* __restrict__ lf, const float* __restrict__ gf,
                                              float* __restrict__ out) {
    __shared__ float tile[32][33];
    int n0 = blockIdx.x * 32, c0 = blockIdx.y * 32;
    int tx = threadIdx.x, ty = threadIdx.y;
#pragma unroll
    for (int k = 0; k < 4; ++k) {
        int n = n0 + ty + k * 8, c = c0 + tx;
        tile[ty + k * 8][tx] = lf[(size_t)n * C_DIM + c] + gf[(size_t)n * C_DIM + c];
    }
    __syncthreads();
#pragma unroll
    for (int k = 0; k < 4; ++k) {
        int c = c0 + ty + k * 8, n = n0 + tx;
        float z = tile[tx][ty + k * 8];
        float sg = 1.0f / (1.0f + __expf(-z));
        out[(size_t)c * N_TOK + n] = x[(size_t)c * N_TOK + n] * sg;
    }
}

extern "C" void kernel_launch(void* const* d_in, const int* in_sizes, int n_in,
                              void* d_out, int out_size, void* d_ws, size_t ws_size,
                              hipStream_t stream) {
    const float* x        = (const float*)d_in[0];
    const float* l_n1_g   = (const float*)d_in[1];
    const float* l_n1_b   = (const float*)d_in[2];
    const float* l_qkv_w  = (const float*)d_in[3];
    const float* l_proj_w = (const float*)d_in[4];
    const float* l_proj_b = (const float*)d_in[5];
    const float* l_n2_g   = (const float*)d_in[6];
    const float* l_n2_b   = (const float*)d_in[7];
    const float* l_fc1_w  = (const float*)d_in[8];
    const float* l_fc1_b  = (const float*)d_in[9];
    const float* l_fc2_w  = (const float*)d_in[10];
    const float* l_fc2_b  = (const float*)d_in[11];
    const float* g_n1_g   = (const float*)d_in[12];
    const float* g_n1_b   = (const float*)d_in[13];
    const float* g_qkv_w  = (const float*)d_in[14];
    const float* g_proj_w = (const float*)d_in[15];
    const float* g_proj_b = (const float*)d_in[16];
    const float* g_n2_g   = (const float*)d_in[17];
    const float* g_n2_b   = (const float*)d_in[18];
    const float* g_fc1_w  = (const float*)d_in[19];
    const float* g_fc1_b  = (const float*)d_in[20];
    const float* g_fc2_w  = (const float*)d_in[21];
    const float* g_fc2_b  = (const float*)d_in[22];
    const float* g_ke_w   = (const float*)d_in[23];
    const float* g_ve_w   = (const float*)d_in[24];
    const float* g_nk_g   = (const float*)d_in[25];
    const float* g_nk_b   = (const float*)d_in[26];
    const float* g_nv_g   = (const float*)d_in[27];
    const float* g_nv_b   = (const float*)d_in[28];
    float* out = (float*)d_out;

    char* base = (char*)d_ws;
    float* xt     = (float*)(base);                        // 0-4 MB
    float* t1_l   = (float*)(base + (4ull  << 20));        // 4-8 MB
    float* t1_g   = (float*)(base + (8ull  << 20));        // 8-12 MB
    short* yA16   = (short*)(base + (12ull << 20));        // 12-14 MB (later t2_l)
    short* yG16   = (short*)(base + (14ull << 20));        // 14-16 MB (later t2_g)
    short* t2_l   = yA16;
    short* t2_g   = yG16;
    float* locfin = (float*)(base + (12ull << 20));        // 12-16 MB (after fc1)
    short* obuf_l = (short*)(base + (16ull << 20));        // 16-18 MB
    short* obuf_g = (short*)(base + (18ull << 20));        // 18-20 MB
    float* glofin = (float*)(base + (16ull << 20));        // 16-20 MB (after proj)
    short* qkv_l  = (short*)(base + (20ull << 20));        // 20-26 MB
    short* qkv_g  = (short*)(base + (26ull << 20));        // 26-32 MB
    short* h1_l   = (short*)(base + (32ull << 20));        // 32-40 MB
    float* kpart  = (float*)(base + (32ull << 20));        // 32-34 MB (pre-fc1)
    float* vpart  = (float*)(base + (34ull << 20));        // 34-36 MB (pre-fc1)
    short* h1_g   = (short*)(base + (40ull << 20));        // 40-48 MB
    short* kg16   = (short*)(base + (40ull << 20));        // 40-42 MB (pre-fc1)
    short* vg16   = (short*)(base + (42ull << 20));        // 42-44 MB (pre-fc1)
    float* krb    = (float*)(base + (48ull << 20));        // 48-48.5 MB [8][1024][16]
    float* vrb    = (float*)(base + (48ull << 20) + (512ull << 10)); // 48.5-49
    short* wts    = (short*)(base + (49ull << 20));        // ~1.3 MB

    const int L_QKV = 0,      L_PROJ = 49152, L_FC1 = 65536,  L_FC2 = 131072;
    const int G_QKV = 196608, G_PROJ = 245760, G_FC1 = 262144, G_FC2 = 327680;
    const int G_KE  = 393216, G_VE   = 524288;

    CvtArgs ca;
    ca.d[0] = {l_qkv_w,  wts + L_QKV,  49152, 0};
    ca.d[1] = {l_proj_w, wts + L_PROJ, 16384, 0};
    ca.d[2] = {l_fc1_w,  wts + L_FC1,  65536, 0};
    ca.d[3] = {l_fc2_w,  wts + L_FC2,  65536, 0};
    ca.d[4] = {g_qkv_w,  wts + G_QKV,  49152, 0};
    ca.d[5] = {g_proj_w, wts + G_PROJ, 16384, 0};
    ca.d[6] = {g_fc1_w,  wts + G_FC1,  65536, 0};
    ca.d[7] = {g_fc2_w,  wts + G_FC2,  65536, 0};
    ca.d[8] = {g_ke_w,   wts + G_KE,  131072, 0};
    ca.d[9] = {g_ve_w,   wts + G_VE,  131072, 0};

    // 1-3: preamble
    cvtw_k<<<dim3(32, 10), 256, 0, stream>>>(ca);
    transpose_k<<<dim3(256, 4), dim3(32, 8), 0, stream>>>(x, xt);
    ln_token_k<<<2048, 256, 0, stream>>>(xt, l_n1_g, l_n1_b, yA16, g_n1_g, g_n1_b, yG16);

    // 4: both qkv GEMMs in one launch
    MArgs a_qkv = {{yA16, yG16}, {wts + L_QKV, wts + G_QKV}, {nullptr, nullptr}, {nullptr, nullptr}, {qkv_l, qkv_g}};
    mgemm_k<0><<<dim3(64, 3, 2), 256, 0, stream>>>(a_qkv, N_TOK, 384, 128, 0);

    // 5-6: local attention; global gather
    local_attn_k<<<256, dim3(32, 8), 0, stream>>>(qkv_l, obuf_l);
    gather_k<<<4096, 256, 0, stream>>>(qkv_g, kg16, vg16);

    // 7: both conv reductions, split-K x4, one launch
    MArgs a_cv = {{kg16, vg16}, {wts + G_KE, wts + G_VE}, {nullptr, nullptr}, {nullptr, nullptr}, {kpart, vpart}};
    mgemm_k<3><<<dim3(8, 1, 8), 256, 0, stream>>>(a_cv, NR, 128, 1024, 256);

    // 8: head-LN for K and V
    ln_head_sum_k<<<64, 256, 0, stream>>>(kpart, vpart, g_nk_g, g_nk_b, g_nv_g, g_nv_b, krb, vrb);

    // 9: global attention
    gattn_k<<<dim3(512, 8), 256, 0, stream>>>(qkv_g, krb, vrb, obuf_g);

    // 10: both proj GEMMs (+bias+residual)
    MArgs a_pj = {{obuf_l, obuf_g}, {wts + L_PROJ, wts + G_PROJ}, {l_proj_b, g_proj_b}, {xt, xt}, {t1_l, t1_g}};
    mgemm_k<1><<<dim3(64, 1, 2), 256, 0, stream>>>(a_pj, N_TOK, 128, 128, 0);

    // 11: both second LNs
    ln2_pair_k<<<4096, 256, 0, stream>>>(t1_l, l_n2_g, l_n2_b, t2_l, t1_g, g_n2_g, g_n2_b, t2_g);

    // 12: both fc1 GEMMs (+bias+gelu)
    MArgs a_f1 = {{t2_l, t2_g}, {wts + L_FC1, wts + G_FC1}, {l_fc1_b, g_fc1_b}, {nullptr, nullptr}, {h1_l, h1_g}};
    mgemm_k<2><<<dim3(64, 4, 2), 256, 0, stream>>>(a_f1, N_TOK, 512, 128, 0);

    // 13: both fc2 GEMMs (+bias+residual)
    MArgs a_f2 = {{h1_l, h1_g}, {wts + L_FC2, wts + G_FC2}, {l_fc2_b, g_fc2_b}, {t1_l, t1_g}, {locfin, glofin}};
    mgemm_k<1><<<dim3(64, 1, 2), 256, 0, stream>>>(a_f2, N_TOK, 128, 512, 0);

    // 14: gate
    gate_k<<<dim3(256, 4), dim3(32, 8), 0, stream>>>(x, locfin, glofin, out);
}

// Round 5
// 257.116 us; speedup vs baseline: 1.3286x; 1.3286x over previous
//
#include <hip/hip_runtime.h>
#include <math.h>

#define N_TOK 8192
#define C_DIM 128
#define NHD   8
#define HDIM  16
#define NR    1024
#define EPSV  1e-5f
#define QK_SCALE 0.25f

typedef __attribute__((ext_vector_type(8))) short short8;
typedef __attribute__((ext_vector_type(4))) float f32x4;

__device__ __forceinline__ float gelu_f(float v) {
    return 0.5f * v * (1.0f + erff(v * 0.70710678118654752f));
}
__device__ __forceinline__ float uaf(unsigned int u) {
    union { unsigned int u; float f; } x; x.u = u; return x.f;
}
__device__ __forceinline__ short f2b(float v) {
    union { float f; unsigned int u; } x; x.f = v;
    unsigned int r = x.u + 0x7fffu + ((x.u >> 16) & 1u);
    return (short)(r >> 16);
}
// load 16 bf16 (32B, 16B-aligned) -> 16 floats
__device__ __forceinline__ void ld16bf(const short* p, float* d) {
    uint4 a = *(const uint4*)p;
    uint4 b = *(const uint4*)(p + 8);
    d[0]  = uaf(a.x << 16); d[1]  = uaf(a.x & 0xffff0000u);
    d[2]  = uaf(a.y << 16); d[3]  = uaf(a.y & 0xffff0000u);
    d[4]  = uaf(a.z << 16); d[5]  = uaf(a.z & 0xffff0000u);
    d[6]  = uaf(a.w << 16); d[7]  = uaf(a.w & 0xffff0000u);
    d[8]  = uaf(b.x << 16); d[9]  = uaf(b.x & 0xffff0000u);
    d[10] = uaf(b.y << 16); d[11] = uaf(b.y & 0xffff0000u);
    d[12] = uaf(b.z << 16); d[13] = uaf(b.z & 0xffff0000u);
    d[14] = uaf(b.w << 16); d[15] = uaf(b.w & 0xffff0000u);
}

// ---------------- weight fp32 -> bf16 conversion ----------------
struct CvtDesc { const float* src; short* dst; int n; int pad; };
struct CvtArgs { CvtDesc d[10]; };
__global__ __launch_bounds__(256) void cvtw_k(CvtArgs a) {
    CvtDesc dd = a.d[blockIdx.y];
    for (int i = blockIdx.x * 256 + threadIdx.x; i < dd.n; i += gridDim.x * 256)
        dd.dst[i] = f2b(dd.src[i]);
}

// ---------------- transpose x (C,N) -> xt (N,C) f32 ----------------
__global__ __launch_bounds__(256) void transpose_k(const float* __restrict__ x,
                                                   float* __restrict__ xt) {
    __shared__ float tile[32][33];
    int n0 = blockIdx.x * 32, c0 = blockIdx.y * 32;
    int tx = threadIdx.x, ty = threadIdx.y;
#pragma unroll
    for (int k = 0; k < 4; ++k)
        tile[ty + k * 8][tx] = x[(size_t)(c0 + ty + k * 8) * N_TOK + n0 + tx];
    __syncthreads();
#pragma unroll
    for (int k = 0; k < 4; ++k)
        xt[(size_t)(n0 + ty + k * 8) * C_DIM + c0 + tx] = tile[tx][ty + k * 8];
}

// ---------------- first LN: fp32 in, two bf16 outputs (local & global gammas) -------
__global__ __launch_bounds__(256) void ln_token_k(const float* __restrict__ in,
                                                  const float* __restrict__ g1, const float* __restrict__ b1,
                                                  short* __restrict__ o1,
                                                  const float* __restrict__ g2, const float* __restrict__ b2,
                                                  short* __restrict__ o2) {
    int lane = threadIdx.x & 63;
    int n = blockIdx.x * 4 + (threadIdx.x >> 6);
    float v0 = in[(size_t)n * C_DIM + lane];
    float v1 = in[(size_t)n * C_DIM + 64 + lane];
    float s = v0 + v1, sq = v0 * v0 + v1 * v1;
#pragma unroll
    for (int off = 32; off >= 1; off >>= 1) {
        s += __shfl_xor(s, off);
        sq += __shfl_xor(sq, off);
    }
    float m = s * (1.0f / 128.0f);
    float var = sq * (1.0f / 128.0f) - m * m;
    float rs = rsqrtf(var + EPSV);
    float h0 = (v0 - m) * rs, h1 = (v1 - m) * rs;
    o1[(size_t)n * C_DIM + lane]      = f2b(h0 * g1[lane] + b1[lane]);
    o1[(size_t)n * C_DIM + 64 + lane] = f2b(h1 * g1[lane + 64] + b1[lane + 64]);
    o2[(size_t)n * C_DIM + lane]      = f2b(h0 * g2[lane] + b2[lane]);
    o2[(size_t)n * C_DIM + 64 + lane] = f2b(h1 * g2[lane + 64] + b2[lane + 64]);
}

// ---------------- second LN, paired across branches (one launch) ----------------
__global__ __launch_bounds__(256) void ln2_pair_k(const float* __restrict__ in0,
                                                  const float* __restrict__ g0, const float* __restrict__ b0,
                                                  short* __restrict__ o0,
                                                  const float* __restrict__ in1,
                                                  const float* __restrict__ g1, const float* __restrict__ b1,
                                                  short* __restrict__ o1) {
    int blk = blockIdx.x;
    bool sel = blk >= 2048;
    blk &= 2047;
    const float* in = sel ? in1 : in0;
    const float* g  = sel ? g1 : g0;
    const float* b  = sel ? b1 : b0;
    short* o        = sel ? o1 : o0;
    int lane = threadIdx.x & 63;
    int n = blk * 4 + (threadIdx.x >> 6);
    float v0 = in[(size_t)n * C_DIM + lane];
    float v1 = in[(size_t)n * C_DIM + 64 + lane];
    float s = v0 + v1, sq = v0 * v0 + v1 * v1;
#pragma unroll
    for (int off = 32; off >= 1; off >>= 1) {
        s += __shfl_xor(s, off);
        sq += __shfl_xor(sq, off);
    }
    float m = s * (1.0f / 128.0f);
    float var = sq * (1.0f / 128.0f) - m * m;
    float rs = rsqrtf(var + EPSV);
    o[(size_t)n * C_DIM + lane]      = f2b((v0 - m) * rs * g[lane] + b[lane]);
    o[(size_t)n * C_DIM + 64 + lane] = f2b((v1 - m) * rs * g[lane + 64] + b[lane + 64]);
}

// ---------------- bf16 MFMA GEMM, branch-paired via blockIdx.z ----------------
struct MArgs {
    const short* A[2]; const short* W[2];
    const float* bias[2]; const float* res[2];
    void* out[2];
};
template <int EPI>
__global__ __launch_bounds__(256) void mgemm_k(MArgs ga, int M, int N, int K, int kslice) {
    int zi    = (EPI == 3) ? (blockIdx.z >> 2) : blockIdx.z;
    int slice = (EPI == 3) ? (blockIdx.z & 3) : 0;
    const short* A = ga.A[zi];
    const short* W = ga.W[zi];
    __shared__ short As[128 * 64];
    __shared__ short Bs[128 * 64];
    int t = threadIdx.x;
    int w = t >> 6, l = t & 63;
    int m0 = blockIdx.x * 128, n0 = blockIdx.y * 128;
    int wm = (w >> 1) * 64, wn = (w & 1) * 64;
    int kbeg = (EPI == 3) ? slice * kslice : 0;
    int kend = kbeg + ((EPI == 3) ? kslice : K);

    f32x4 acc[4][4];
#pragma unroll
    for (int a = 0; a < 4; ++a)
#pragma unroll
        for (int b = 0; b < 4; ++b) acc[a][b] = f32x4{0.f, 0.f, 0.f, 0.f};

    for (int k0 = kbeg; k0 < kend; k0 += 64) {
        __syncthreads();
#pragma unroll
        for (int c = 0; c < 4; ++c) {
            int chunk = c * 256 + t;
            int row = chunk >> 3;
            int slot = chunk & 7;
            int ss = slot ^ (row & 7);     // XOR swizzle (T2)
            uint4 av = *(const uint4*)(A + (size_t)(m0 + row) * K + k0 + slot * 8);
            *(uint4*)(As + row * 64 + ss * 8) = av;
            uint4 wv = *(const uint4*)(W + (size_t)(n0 + row) * K + k0 + slot * 8);
            *(uint4*)(Bs + row * 64 + ss * 8) = wv;
        }
        __syncthreads();
#pragma unroll
        for (int kk = 0; kk < 2; ++kk) {
            short8 af[4], bf[4];
            int sl = kk * 4 + (l >> 4);
#pragma unroll
            for (int mf = 0; mf < 4; ++mf) {
                int row = wm + mf * 16 + (l & 15);
                af[mf] = *(const short8*)(As + row * 64 + (sl ^ (row & 7)) * 8);
            }
#pragma unroll
            for (int nf = 0; nf < 4; ++nf) {
                int row = wn + nf * 16 + (l & 15);
                bf[nf] = *(const short8*)(Bs + row * 64 + (sl ^ (row & 7)) * 8);
            }
#pragma unroll
            for (int mf = 0; mf < 4; ++mf)
#pragma unroll
                for (int nf = 0; nf < 4; ++nf)
                    acc[mf][nf] = __builtin_amdgcn_mfma_f32_16x16x32_bf16(
                        af[mf], bf[nf], acc[mf][nf], 0, 0, 0);
        }
    }

    // C/D layout: col = lane&15, row = (lane>>4)*4 + reg
#pragma unroll
    for (int mf = 0; mf < 4; ++mf) {
#pragma unroll
        for (int nf = 0; nf < 4; ++nf) {
            int col = n0 + wn + nf * 16 + (l & 15);
#pragma unroll
            for (int j = 0; j < 4; ++j) {
                int row = m0 + wm + mf * 16 + (l >> 4) * 4 + j;
                float v = acc[mf][nf][j];
                if (EPI == 0) {
                    ((short*)ga.out[zi])[(size_t)row * N + col] = f2b(v);
                } else if (EPI == 1) {
                    v += ga.bias[zi][col] + ga.res[zi][(size_t)row * N + col];
                    ((float*)ga.out[zi])[(size_t)row * N + col] = v;
                } else if (EPI == 2) {
                    v = gelu_f(v + ga.bias[zi][col]);
                    ((short*)ga.out[zi])[(size_t)row * N + col] = f2b(v);
                } else {
                    ((float*)ga.out[zi])[(size_t)slice * M * N + (size_t)row * N + col] = v;
                }
            }
        }
    }
}

// ---------------- local patch attention, bf16 in/out ----------------
__global__ __launch_bounds__(256) void local_attn_k(const short* __restrict__ qkv,
                                                    short* __restrict__ ob) {
    __shared__ float ks[NHD][32][HDIM];
    __shared__ float vs[NHD][32][HDIM];
    int m = threadIdx.x, h = threadIdx.y, r = blockIdx.x;
    int zd = r >> 6, zh = (r >> 3) & 7, zw = r & 7;
    int pd = m >> 4, ph = (m >> 2) & 3, pw = m & 3;
    int n = (zd * 2 + pd) * 1024 + (zh * 4 + ph) * 32 + (zw * 4 + pw);
    const short* base = qkv + (size_t)n * 384 + h * HDIM;
    float q[16], kt[16], vt[16];
    ld16bf(base, q);
    ld16bf(base + 128, kt);
    ld16bf(base + 256, vt);
#pragma unroll
    for (int d = 0; d < 16; ++d) { ks[h][m][d] = kt[d]; vs[h][m][d] = vt[d]; }
    __syncthreads();
    float s[32];
#pragma unroll
    for (int j = 0; j < 32; ++j) {
        float d = 0.f;
#pragma unroll
        for (int dd = 0; dd < 16; ++dd) d += q[dd] * ks[h][j][dd];
        s[j] = __expf(d * QK_SCALE);   // bounded scores: exp-direct
    }
    float sum = 0.f;
#pragma unroll
    for (int j = 0; j < 32; ++j) sum += s[j];
    float inv = 1.0f / sum;
    float oo[16] = {};
#pragma unroll
    for (int j = 0; j < 32; ++j) {
        float p = s[j] * inv;
#pragma unroll
        for (int dd = 0; dd < 16; ++dd) oo[dd] += p * vs[h][j][dd];
    }
    // torch-faithful quirk: o (NH,Npl,HD) -> swap(-1,-2) -> reshape (Npl, C)
#pragma unroll
    for (int dd = 0; dd < 16; ++dd) {
        int n2 = h * 4 + (dd >> 2);
        int c2 = (dd & 3) * 32 + m;
        int pd2 = n2 >> 4, ph2 = (n2 >> 2) & 3, pw2 = n2 & 3;
        int nn = (zd * 2 + pd2) * 1024 + (zh * 4 + ph2) * 32 + (zw * 4 + pw2);
        ob[(size_t)nn * C_DIM + c2] = f2b(oo[dd]);
    }
}

// ---------------- gather reduced K/V conv inputs ----------------
__global__ __launch_bounds__(256) void gather_k(const short* __restrict__ qkv,
                                                short* __restrict__ kg, short* __restrict__ vg) {
    int idx = blockIdx.x * 256 + threadIdx.x;
    int nr = idx >> 10, qq = idx & 1023;
    int ci = qq >> 3, off = qq & 7;
    int od = off >> 2, oh = (off >> 1) & 1, ow = off & 1;
    int d2 = nr >> 8, h2 = (nr >> 4) & 15, w2 = nr & 15;
    int n = (2 * d2 + od) * 1024 + (2 * h2 + oh) * 32 + (2 * w2 + ow);
    kg[idx] = qkv[(size_t)n * 384 + 128 + ci];
    vg[idx] = qkv[(size_t)n * 384 + 256 + ci];
}

// ---------------- sum 4 split-K partials + per-head LN (K and V in one launch) ------
__global__ __launch_bounds__(256) void ln_head_sum_k(const float* __restrict__ kpart,
                                                     const float* __restrict__ vpart,
                                                     const float* __restrict__ gk, const float* __restrict__ bk,
                                                     const float* __restrict__ gv, const float* __restrict__ bv,
                                                     float* __restrict__ kout, float* __restrict__ vout) {
    int idx = blockIdx.x * 256 + threadIdx.x;   // 0..16383
    bool sel = idx >= 8192;
    int id2 = idx & 8191;
    const float* part = sel ? vpart : kpart;
    const float* g    = sel ? gv : gk;
    const float* b    = sel ? bv : bk;
    float* outb       = sel ? vout : kout;
    int nr = id2 >> 3, h = id2 & 7;
    size_t base = (size_t)nr * C_DIM + h * HDIM;
    float v[16] = {};
#pragma unroll
    for (int p = 0; p < 4; ++p) {
        const float* pp = part + (size_t)p * (NR * C_DIM) + base;
#pragma unroll
        for (int d4 = 0; d4 < 4; ++d4) {
            float4 t = *(const float4*)(pp + d4 * 4);
            v[d4 * 4 + 0] += t.x; v[d4 * 4 + 1] += t.y;
            v[d4 * 4 + 2] += t.z; v[d4 * 4 + 3] += t.w;
        }
    }
    float s = 0.f;
#pragma unroll
    for (int i = 0; i < 16; ++i) s += v[i];
    float m = s * (1.0f / 16.0f);
    float sq = 0.f;
#pragma unroll
    for (int i = 0; i < 16; ++i) { float d = v[i] - m; sq += d * d; }
    float rs = rsqrtf(sq * (1.0f / 16.0f) + EPSV);
    float* op = outb + (size_t)h * (NR * HDIM) + (size_t)nr * HDIM;
#pragma unroll
    for (int i = 0; i < 16; ++i) op[i] = (v[i] - m) * rs * g[i] + b[i];
}

// ---------------- global attention v5: LDS-shared K/V, QT=4, no runtime reg index ---
// grid (256, 8); block 256 = 8 groups x 32 lanes; 4 queries per group.
#define KB 256
__global__ __launch_bounds__(256) void gattn_k(const short* __restrict__ qkv,
                                               const float* __restrict__ kr,  // [8][1024][16]
                                               const float* __restrict__ vr,
                                               short* __restrict__ ob) {
    __shared__ float kds[4][KB][4];     // plane-major: conflict-free b128 at 16B stride
    __shared__ float vds[4][KB][4];
    __shared__ float obnc[8][4][16];    // bounce buffer for the final store
    int t = threadIdx.x;
    int h = blockIdx.y;
    int g = t >> 5, i = t & 31;
    int q0 = blockIdx.x * 32 + g * 4;

    float q[4][16];
#pragma unroll
    for (int a = 0; a < 4; ++a) {
        ld16bf(qkv + (size_t)(q0 + a) * 384 + h * HDIM, q[a]);
#pragma unroll
        for (int d = 0; d < 16; ++d) q[a][d] *= QK_SCALE;
    }
    const float* kh = kr + (size_t)h * (NR * HDIM);
    const float* vh = vr + (size_t)h * (NR * HDIM);

    float sm[4] = {0.f, 0.f, 0.f, 0.f};
    float o[4][16] = {};

    for (int c0 = 0; c0 < NR; c0 += KB) {
        __syncthreads();
        {   // stage: thread t owns key row c0+t (64B K + 64B V, coalesced)
            const float* kp = kh + (size_t)(c0 + t) * HDIM;
            const float* vp = vh + (size_t)(c0 + t) * HDIM;
#pragma unroll
            for (int p = 0; p < 4; ++p) {
                *(float4*)&kds[p][t][0] = *(const float4*)(kp + p * 4);
                *(float4*)&vds[p][t][0] = *(const float4*)(vp + p * 4);
            }
        }
        __syncthreads();
#pragma unroll
        for (int kk = 0; kk < KB / 32; ++kk) {
            int j = kk * 32 + i;
            float kv[16];
#pragma unroll
            for (int p = 0; p < 4; ++p)
                *(float4*)&kv[p * 4] = *(const float4*)&kds[p][j][0];
            float p0 = 0.f, p1 = 0.f, p2 = 0.f, p3 = 0.f;
#pragma unroll
            for (int d = 0; d < 16; ++d) {
                p0 += q[0][d] * kv[d]; p1 += q[1][d] * kv[d];
                p2 += q[2][d] * kv[d]; p3 += q[3][d] * kv[d];
            }
            p0 = __expf(p0); p1 = __expf(p1); p2 = __expf(p2); p3 = __expf(p3);
            sm[0] += p0; sm[1] += p1; sm[2] += p2; sm[3] += p3;
            float vv[16];
#pragma unroll
            for (int p = 0; p < 4; ++p)
                *(float4*)&vv[p * 4] = *(const float4*)&vds[p][j][0];
#pragma unroll
            for (int d = 0; d < 16; ++d) {
                o[0][d] += p0 * vv[d]; o[1][d] += p1 * vv[d];
                o[2][d] += p2 * vv[d]; o[3][d] += p3 * vv[d];
            }
        }
    }
    // reduce to lane 0 of each 32-lane group (compile-time indices only)
#pragma unroll
    for (int a = 0; a < 4; ++a) {
#pragma unroll
        for (int off = 16; off >= 1; off >>= 1) sm[a] += __shfl_down(sm[a], off);
#pragma unroll
        for (int d = 0; d < 16; ++d) {
            float v = o[a][d];
#pragma unroll
            for (int off = 16; off >= 1; off >>= 1) v += __shfl_down(v, off);
            o[a][d] = v;
        }
    }
    if (i == 0) {
#pragma unroll
        for (int a = 0; a < 4; ++a) {
            float inv = 1.0f / sm[a];
#pragma unroll
            for (int d = 0; d < 16; ++d) obnc[g][a][d] = o[a][d] * inv;
        }
    }
    __syncthreads();
    if (i < 16) {
#pragma unroll
        for (int a = 0; a < 4; ++a)
            ob[(size_t)(q0 + a) * C_DIM + h * HDIM + i] = f2b(obnc[g][a][i]);
    }
}

// ---------------- final gate: out(C,N) = x * sigmoid(loc + glo) ----------------
__global__ __launch_bounds__(256) void gate_k(const float* __restrict__ x,
                                              const float* __restrict__ lf, const float* __restrict__ gf,
                                              float* __restrict__ out) {
    __shared__ float tile[32][33];
    int n0 = blockIdx.x * 32, c0 = blockIdx.y * 32;
    int tx = threadIdx.x, ty = threadIdx.y;
#pragma unroll
    for (int k = 0; k < 4; ++k) {
        int n = n0 + ty + k * 8, c = c0 + tx;
        tile[ty + k * 8][tx] = lf[(size_t)n * C_DIM + c] + gf[(size_t)n * C_DIM + c];
    }
    __syncthreads();
#pragma unroll
    for (int k = 0; k < 4; ++k) {
        int c = c0 + ty + k * 8, n = n0 + tx;
        float z = tile[tx][ty + k * 8];
        float sg = 1.0f / (1.0f + __expf(-z));
        out[(size_t)c * N_TOK + n] = x[(size_t)c * N_TOK + n] * sg;
    }
}

extern "C" void kernel_launch(void* const* d_in, const int* in_sizes, int n_in,
                              void* d_out, int out_size, void* d_ws, size_t ws_size,
                              hipStream_t stream) {
    const float* x        = (const float*)d_in[0];
    const float* l_n1_g   = (const float*)d_in[1];
    const float* l_n1_b   = (const float*)d_in[2];
    const float* l_qkv_w  = (const float*)d_in[3];
    const float* l_proj_w = (const float*)d_in[4];
    const float* l_proj_b = (const float*)d_in[5];
    const float* l_n2_g   = (const float*)d_in[6];
    const float* l_n2_b   = (const float*)d_in[7];
    const float* l_fc1_w  = (const float*)d_in[8];
    const float* l_fc1_b  = (const float*)d_in[9];
    const float* l_fc2_w  = (const float*)d_in[10];
    const float* l_fc2_b  = (const float*)d_in[11];
    const float* g_n1_g   = (const float*)d_in[12];
    const float* g_n1_b   = (const float*)d_in[13];
    const float* g_qkv_w  = (const float*)d_in[14];
    const float* g_proj_w = (const float*)d_in[15];
    const float* g_proj_b = (const float*)d_in[16];
    const float* g_n2_g   = (const float*)d_in[17];
    const float* g_n2_b   = (const float*)d_in[18];
    const float* g_fc1_w  = (const float*)d_in[19];
    const float* g_fc1_b  = (const float*)d_in[20];
    const float* g_fc2_w  = (const float*)d_in[21];
    const float* g_fc2_b  = (const float*)d_in[22];
    const float* g_ke_w   = (const float*)d_in[23];
    const float* g_ve_w   = (const float*)d_in[24];
    const float* g_nk_g   = (const float*)d_in[25];
    const float* g_nk_b   = (const float*)d_in[26];
    const float* g_nv_g   = (const float*)d_in[27];
    const float* g_nv_b   = (const float*)d_in[28];
    float* out = (float*)d_out;

    char* base = (char*)d_ws;
    float* xt     = (float*)(base);                        // 0-4 MB
    float* t1_l   = (float*)(base + (4ull  << 20));        // 4-8 MB
    float* t1_g   = (float*)(base + (8ull  << 20));        // 8-12 MB
    short* yA16   = (short*)(base + (12ull << 20));        // 12-14 MB (later t2_l)
    short* yG16   = (short*)(base + (14ull << 20));        // 14-16 MB (later t2_g)
    short* t2_l   = yA16;
    short* t2_g   = yG16;
    float* locfin = (float*)(base + (12ull << 20));        // 12-16 MB (after fc1)
    short* obuf_l = (short*)(base + (16ull << 20));        // 16-18 MB
    short* obuf_g = (short*)(base + (18ull << 20));        // 18-20 MB
    float* glofin = (float*)(base + (16ull << 20));        // 16-20 MB (after proj)
    short* qkv_l  = (short*)(base + (20ull << 20));        // 20-26 MB
    short* qkv_g  = (short*)(base + (26ull << 20));        // 26-32 MB
    short* h1_l   = (short*)(base + (32ull << 20));        // 32-40 MB
    float* kpart  = (float*)(base + (32ull << 20));        // 32-34 MB (pre-fc1)
    float* vpart  = (float*)(base + (34ull << 20));        // 34-36 MB (pre-fc1)
    short* h1_g   = (short*)(base + (40ull << 20));        // 40-48 MB
    short* kg16   = (short*)(base + (40ull << 20));        // 40-42 MB (pre-fc1)
    short* vg16   = (short*)(base + (42ull << 20));        // 42-44 MB (pre-fc1)
    float* krb    = (float*)(base + (48ull << 20));        // 48-48.5 MB [8][1024][16]
    float* vrb    = (float*)(base + (48ull << 20) + (512ull << 10)); // 48.5-49
    short* wts    = (short*)(base + (49ull << 20));        // ~1.3 MB

    const int L_QKV = 0,      L_PROJ = 49152, L_FC1 = 65536,  L_FC2 = 131072;
    const int G_QKV = 196608, G_PROJ = 245760, G_FC1 = 262144, G_FC2 = 327680;
    const int G_KE  = 393216, G_VE   = 524288;

    CvtArgs ca;
    ca.d[0] = {l_qkv_w,  wts + L_QKV,  49152, 0};
    ca.d[1] = {l_proj_w, wts + L_PROJ, 16384, 0};
    ca.d[2] = {l_fc1_w,  wts + L_FC1,  65536, 0};
    ca.d[3] = {l_fc2_w,  wts + L_FC2,  65536, 0};
    ca.d[4] = {g_qkv_w,  wts + G_QKV,  49152, 0};
    ca.d[5] = {g_proj_w, wts + G_PROJ, 16384, 0};
    ca.d[6] = {g_fc1_w,  wts + G_FC1,  65536, 0};
    ca.d[7] = {g_fc2_w,  wts + G_FC2,  65536, 0};
    ca.d[8] = {g_ke_w,   wts + G_KE,  131072, 0};
    ca.d[9] = {g_ve_w,   wts + G_VE,  131072, 0};

    // 1-3: preamble
    cvtw_k<<<dim3(32, 10), 256, 0, stream>>>(ca);
    transpose_k<<<dim3(256, 4), dim3(32, 8), 0, stream>>>(x, xt);
    ln_token_k<<<2048, 256, 0, stream>>>(xt, l_n1_g, l_n1_b, yA16, g_n1_g, g_n1_b, yG16);

    // 4: both qkv GEMMs in one launch
    MArgs a_qkv = {{yA16, yG16}, {wts + L_QKV, wts + G_QKV}, {nullptr, nullptr}, {nullptr, nullptr}, {qkv_l, qkv_g}};
    mgemm_k<0><<<dim3(64, 3, 2), 256, 0, stream>>>(a_qkv, N_TOK, 384, 128, 0);

    // 5-6: local attention; global gather
    local_attn_k<<<256, dim3(32, 8), 0, stream>>>(qkv_l, obuf_l);
    gather_k<<<4096, 256, 0, stream>>>(qkv_g, kg16, vg16);

    // 7: both conv reductions, split-K x4, one launch
    MArgs a_cv = {{kg16, vg16}, {wts + G_KE, wts + G_VE}, {nullptr, nullptr}, {nullptr, nullptr}, {kpart, vpart}};
    mgemm_k<3><<<dim3(8, 1, 8), 256, 0, stream>>>(a_cv, NR, 128, 1024, 256);

    // 8: head-LN for K and V
    ln_head_sum_k<<<64, 256, 0, stream>>>(kpart, vpart, g_nk_g, g_nk_b, g_nv_g, g_nv_b, krb, vrb);

    // 9: global attention
    gattn_k<<<dim3(256, 8), 256, 0, stream>>>(qkv_g, krb, vrb, obuf_g);

    // 10: both proj GEMMs (+bias+residual)
    MArgs a_pj = {{obuf_l, obuf_g}, {wts + L_PROJ, wts + G_PROJ}, {l_proj_b, g_proj_b}, {xt, xt}, {t1_l, t1_g}};
    mgemm_k<1><<<dim3(64, 1, 2), 256, 0, stream>>>(a_pj, N_TOK, 128, 128, 0);

    // 11: both second LNs
    ln2_pair_k<<<4096, 256, 0, stream>>>(t1_l, l_n2_g, l_n2_b, t2_l, t1_g, g_n2_g, g_n2_b, t2_g);

    // 12: both fc1 GEMMs (+bias+gelu)
    MArgs a_f1 = {{t2_l, t2_g}, {wts + L_FC1, wts + G_FC1}, {l_fc1_b, g_fc1_b}, {nullptr, nullptr}, {h1_l, h1_g}};
    mgemm_k<2><<<dim3(64, 4, 2), 256, 0, stream>>>(a_f1, N_TOK, 512, 128, 0);

    // 13: both fc2 GEMMs (+bias+residual)
    MArgs a_f2 = {{h1_l, h1_g}, {wts + L_FC2, wts + G_FC2}, {l_fc2_b, g_fc2_b}, {t1_l, t1_g}, {locfin, glofin}};
    mgemm_k<1><<<dim3(64, 1, 2), 256, 0, stream>>>(a_f2, N_TOK, 128, 512, 0);

    // 14: gate
    gate_k<<<dim3(256, 4), dim3(32, 8), 0, stream>>>(x, locfin, glofin, out);
}

// Round 6
// 143.779 us; speedup vs baseline: 2.3759x; 1.7883x over previous
//
#include <hip/hip_runtime.h>
#include <math.h>

#define N_TOK 8192
#define C_DIM 128
#define NHD   8
#define HDIM  16
#define NR    1024
#define EPSV  1e-5f
#define QK_SCALE 0.25f

typedef __attribute__((ext_vector_type(8))) short short8;
typedef __attribute__((ext_vector_type(4))) float f32x4;

__device__ __forceinline__ float gelu_f(float v) {
    return 0.5f * v * (1.0f + erff(v * 0.70710678118654752f));
}
__device__ __forceinline__ float uaf(unsigned int u) {
    union { unsigned int u; float f; } x; x.u = u; return x.f;
}
__device__ __forceinline__ short f2b(float v) {
    union { float f; unsigned int u; } x; x.f = v;
    unsigned int r = x.u + 0x7fffu + ((x.u >> 16) & 1u);
    return (short)(r >> 16);
}
// load 16 bf16 (32B, 16B-aligned) -> 16 floats
__device__ __forceinline__ void ld16bf(const short* p, float* d) {
    uint4 a = *(const uint4*)p;
    uint4 b = *(const uint4*)(p + 8);
    d[0]  = uaf(a.x << 16); d[1]  = uaf(a.x & 0xffff0000u);
    d[2]  = uaf(a.y << 16); d[3]  = uaf(a.y & 0xffff0000u);
    d[4]  = uaf(a.z << 16); d[5]  = uaf(a.z & 0xffff0000u);
    d[6]  = uaf(a.w << 16); d[7]  = uaf(a.w & 0xffff0000u);
    d[8]  = uaf(b.x << 16); d[9]  = uaf(b.x & 0xffff0000u);
    d[10] = uaf(b.y << 16); d[11] = uaf(b.y & 0xffff0000u);
    d[12] = uaf(b.z << 16); d[13] = uaf(b.z & 0xffff0000u);
    d[14] = uaf(b.w << 16); d[15] = uaf(b.w & 0xffff0000u);
}

// ---------------- weight fp32 -> bf16 conversion ----------------
struct CvtDesc { const float* src; short* dst; int n; int pad; };
struct CvtArgs { CvtDesc d[10]; };
__global__ __launch_bounds__(256) void cvtw_k(CvtArgs a) {
    CvtDesc dd = a.d[blockIdx.y];
    for (int i = blockIdx.x * 256 + threadIdx.x; i < dd.n; i += gridDim.x * 256)
        dd.dst[i] = f2b(dd.src[i]);
}

// ---------------- transpose x (C,N) -> xt (N,C) f32 ----------------
__global__ __launch_bounds__(256) void transpose_k(const float* __restrict__ x,
                                                   float* __restrict__ xt) {
    __shared__ float tile[32][33];
    int n0 = blockIdx.x * 32, c0 = blockIdx.y * 32;
    int tx = threadIdx.x, ty = threadIdx.y;
#pragma unroll
    for (int k = 0; k < 4; ++k)
        tile[ty + k * 8][tx] = x[(size_t)(c0 + ty + k * 8) * N_TOK + n0 + tx];
    __syncthreads();
#pragma unroll
    for (int k = 0; k < 4; ++k)
        xt[(size_t)(n0 + ty + k * 8) * C_DIM + c0 + tx] = tile[tx][ty + k * 8];
}

// ---------------- first LN: fp32 in, two bf16 outputs (local & global gammas) -------
__global__ __launch_bounds__(256) void ln_token_k(const float* __restrict__ in,
                                                  const float* __restrict__ g1, const float* __restrict__ b1,
                                                  short* __restrict__ o1,
                                                  const float* __restrict__ g2, const float* __restrict__ b2,
                                                  short* __restrict__ o2) {
    int lane = threadIdx.x & 63;
    int n = blockIdx.x * 4 + (threadIdx.x >> 6);
    float v0 = in[(size_t)n * C_DIM + lane];
    float v1 = in[(size_t)n * C_DIM + 64 + lane];
    float s = v0 + v1, sq = v0 * v0 + v1 * v1;
#pragma unroll
    for (int off = 32; off >= 1; off >>= 1) {
        s += __shfl_xor(s, off);
        sq += __shfl_xor(sq, off);
    }
    float m = s * (1.0f / 128.0f);
    float var = sq * (1.0f / 128.0f) - m * m;
    float rs = rsqrtf(var + EPSV);
    float h0 = (v0 - m) * rs, h1 = (v1 - m) * rs;
    o1[(size_t)n * C_DIM + lane]      = f2b(h0 * g1[lane] + b1[lane]);
    o1[(size_t)n * C_DIM + 64 + lane] = f2b(h1 * g1[lane + 64] + b1[lane + 64]);
    o2[(size_t)n * C_DIM + lane]      = f2b(h0 * g2[lane] + b2[lane]);
    o2[(size_t)n * C_DIM + 64 + lane] = f2b(h1 * g2[lane + 64] + b2[lane + 64]);
}

// ---------------- second LN, paired across branches (one launch) ----------------
__global__ __launch_bounds__(256) void ln2_pair_k(const float* __restrict__ in0,
                                                  const float* __restrict__ g0, const float* __restrict__ b0,
                                                  short* __restrict__ o0,
                                                  const float* __restrict__ in1,
                                                  const float* __restrict__ g1, const float* __restrict__ b1,
                                                  short* __restrict__ o1) {
    int blk = blockIdx.x;
    bool sel = blk >= 2048;
    blk &= 2047;
    const float* in = sel ? in1 : in0;
    const float* g  = sel ? g1 : g0;
    const float* b  = sel ? b1 : b0;
    short* o        = sel ? o1 : o0;
    int lane = threadIdx.x & 63;
    int n = blk * 4 + (threadIdx.x >> 6);
    float v0 = in[(size_t)n * C_DIM + lane];
    float v1 = in[(size_t)n * C_DIM + 64 + lane];
    float s = v0 + v1, sq = v0 * v0 + v1 * v1;
#pragma unroll
    for (int off = 32; off >= 1; off >>= 1) {
        s += __shfl_xor(s, off);
        sq += __shfl_xor(sq, off);
    }
    float m = s * (1.0f / 128.0f);
    float var = sq * (1.0f / 128.0f) - m * m;
    float rs = rsqrtf(var + EPSV);
    o[(size_t)n * C_DIM + lane]      = f2b((v0 - m) * rs * g[lane] + b[lane]);
    o[(size_t)n * C_DIM + 64 + lane] = f2b((v1 - m) * rs * g[lane + 64] + b[lane + 64]);
}

// ---------------- bf16 MFMA GEMM, branch-paired via blockIdx.z ----------------
struct MArgs {
    const short* A[2]; const short* W[2];
    const float* bias[2]; const float* res[2];
    void* out[2];
};
template <int EPI>
__global__ __launch_bounds__(256) void mgemm_k(MArgs ga, int M, int N, int K, int kslice) {
    int zi    = (EPI == 3) ? (blockIdx.z >> 2) : blockIdx.z;
    int slice = (EPI == 3) ? (blockIdx.z & 3) : 0;
    const short* A = ga.A[zi];
    const short* W = ga.W[zi];
    __shared__ short As[128 * 64];
    __shared__ short Bs[128 * 64];
    int t = threadIdx.x;
    int w = t >> 6, l = t & 63;
    int m0 = blockIdx.x * 128, n0 = blockIdx.y * 128;
    int wm = (w >> 1) * 64, wn = (w & 1) * 64;
    int kbeg = (EPI == 3) ? slice * kslice : 0;
    int kend = kbeg + ((EPI == 3) ? kslice : K);

    f32x4 acc[4][4];
#pragma unroll
    for (int a = 0; a < 4; ++a)
#pragma unroll
        for (int b = 0; b < 4; ++b) acc[a][b] = f32x4{0.f, 0.f, 0.f, 0.f};

    for (int k0 = kbeg; k0 < kend; k0 += 64) {
        __syncthreads();
#pragma unroll
        for (int c = 0; c < 4; ++c) {
            int chunk = c * 256 + t;
            int row = chunk >> 3;
            int slot = chunk & 7;
            int ss = slot ^ (row & 7);     // XOR swizzle (T2)
            uint4 av = *(const uint4*)(A + (size_t)(m0 + row) * K + k0 + slot * 8);
            *(uint4*)(As + row * 64 + ss * 8) = av;
            uint4 wv = *(const uint4*)(W + (size_t)(n0 + row) * K + k0 + slot * 8);
            *(uint4*)(Bs + row * 64 + ss * 8) = wv;
        }
        __syncthreads();
#pragma unroll
        for (int kk = 0; kk < 2; ++kk) {
            short8 af[4], bf[4];
            int sl = kk * 4 + (l >> 4);
#pragma unroll
            for (int mf = 0; mf < 4; ++mf) {
                int row = wm + mf * 16 + (l & 15);
                af[mf] = *(const short8*)(As + row * 64 + (sl ^ (row & 7)) * 8);
            }
#pragma unroll
            for (int nf = 0; nf < 4; ++nf) {
                int row = wn + nf * 16 + (l & 15);
                bf[nf] = *(const short8*)(Bs + row * 64 + (sl ^ (row & 7)) * 8);
            }
#pragma unroll
            for (int mf = 0; mf < 4; ++mf)
#pragma unroll
                for (int nf = 0; nf < 4; ++nf)
                    acc[mf][nf] = __builtin_amdgcn_mfma_f32_16x16x32_bf16(
                        af[mf], bf[nf], acc[mf][nf], 0, 0, 0);
        }
    }

    // C/D layout: col = lane&15, row = (lane>>4)*4 + reg
#pragma unroll
    for (int mf = 0; mf < 4; ++mf) {
#pragma unroll
        for (int nf = 0; nf < 4; ++nf) {
            int col = n0 + wn + nf * 16 + (l & 15);
#pragma unroll
            for (int j = 0; j < 4; ++j) {
                int row = m0 + wm + mf * 16 + (l >> 4) * 4 + j;
                float v = acc[mf][nf][j];
                if (EPI == 0) {
                    ((short*)ga.out[zi])[(size_t)row * N + col] = f2b(v);
                } else if (EPI == 1) {
                    v += ga.bias[zi][col] + ga.res[zi][(size_t)row * N + col];
                    ((float*)ga.out[zi])[(size_t)row * N + col] = v;
                } else if (EPI == 2) {
                    v = gelu_f(v + ga.bias[zi][col]);
                    ((short*)ga.out[zi])[(size_t)row * N + col] = f2b(v);
                } else {
                    ((float*)ga.out[zi])[(size_t)slice * M * N + (size_t)row * N + col] = v;
                }
            }
        }
    }
}

// ---------------- local patch attention, bf16 in/out ----------------
__global__ __launch_bounds__(256) void local_attn_k(const short* __restrict__ qkv,
                                                    short* __restrict__ ob) {
    __shared__ float ks[NHD][32][HDIM];
    __shared__ float vs[NHD][32][HDIM];
    int m = threadIdx.x, h = threadIdx.y, r = blockIdx.x;
    int zd = r >> 6, zh = (r >> 3) & 7, zw = r & 7;
    int pd = m >> 4, ph = (m >> 2) & 3, pw = m & 3;
    int n = (zd * 2 + pd) * 1024 + (zh * 4 + ph) * 32 + (zw * 4 + pw);
    const short* base = qkv + (size_t)n * 384 + h * HDIM;
    float q[16], kt[16], vt[16];
    ld16bf(base, q);
    ld16bf(base + 128, kt);
    ld16bf(base + 256, vt);
#pragma unroll
    for (int d = 0; d < 16; ++d) { ks[h][m][d] = kt[d]; vs[h][m][d] = vt[d]; }
    __syncthreads();
    float s[32];
#pragma unroll
    for (int j = 0; j < 32; ++j) {
        float d = 0.f;
#pragma unroll
        for (int dd = 0; dd < 16; ++dd) d += q[dd] * ks[h][j][dd];
        s[j] = __expf(d * QK_SCALE);   // bounded scores: exp-direct
    }
    float sum = 0.f;
#pragma unroll
    for (int j = 0; j < 32; ++j) sum += s[j];
    float inv = 1.0f / sum;
    float oo[16] = {};
#pragma unroll
    for (int j = 0; j < 32; ++j) {
        float p = s[j] * inv;
#pragma unroll
        for (int dd = 0; dd < 16; ++dd) oo[dd] += p * vs[h][j][dd];
    }
    // torch-faithful quirk: o (NH,Npl,HD) -> swap(-1,-2) -> reshape (Npl, C)
#pragma unroll
    for (int dd = 0; dd < 16; ++dd) {
        int n2 = h * 4 + (dd >> 2);
        int c2 = (dd & 3) * 32 + m;
        int pd2 = n2 >> 4, ph2 = (n2 >> 2) & 3, pw2 = n2 & 3;
        int nn = (zd * 2 + pd2) * 1024 + (zh * 4 + ph2) * 32 + (zw * 4 + pw2);
        ob[(size_t)nn * C_DIM + c2] = f2b(oo[dd]);
    }
}

// ---------------- gather reduced K/V conv inputs ----------------
__global__ __launch_bounds__(256) void gather_k(const short* __restrict__ qkv,
                                                short* __restrict__ kg, short* __restrict__ vg) {
    int idx = blockIdx.x * 256 + threadIdx.x;
    int nr = idx >> 10, qq = idx & 1023;
    int ci = qq >> 3, off = qq & 7;
    int od = off >> 2, oh = (off >> 1) & 1, ow = off & 1;
    int d2 = nr >> 8, h2 = (nr >> 4) & 15, w2 = nr & 15;
    int n = (2 * d2 + od) * 1024 + (2 * h2 + oh) * 32 + (2 * w2 + ow);
    kg[idx] = qkv[(size_t)n * 384 + 128 + ci];
    vg[idx] = qkv[(size_t)n * 384 + 256 + ci];
}

// ------- sum 4 split-K partials + per-head LN; K -> bf16 [8][1024][16] (pre-scaled),
//         V -> bf16 transposed [8][16][1024]  (one launch handles both) -------------
__global__ __launch_bounds__(256) void ln_head_sum_k(const float* __restrict__ kpart,
                                                     const float* __restrict__ vpart,
                                                     const float* __restrict__ gk, const float* __restrict__ bk,
                                                     const float* __restrict__ gv, const float* __restrict__ bv,
                                                     short* __restrict__ kout, short* __restrict__ vout) {
    int idx = blockIdx.x * 256 + threadIdx.x;   // 0..16383
    bool sel = idx >= 8192;
    int id2 = idx & 8191;
    const float* part = sel ? vpart : kpart;
    const float* g    = sel ? gv : gk;
    const float* b    = sel ? bv : bk;
    int nr = id2 >> 3, h = id2 & 7;
    size_t base = (size_t)nr * C_DIM + h * HDIM;
    float v[16] = {};
#pragma unroll
    for (int p = 0; p < 4; ++p) {
        const float* pp = part + (size_t)p * (NR * C_DIM) + base;
#pragma unroll
        for (int d4 = 0; d4 < 4; ++d4) {
            float4 t = *(const float4*)(pp + d4 * 4);
            v[d4 * 4 + 0] += t.x; v[d4 * 4 + 1] += t.y;
            v[d4 * 4 + 2] += t.z; v[d4 * 4 + 3] += t.w;
        }
    }
    float s = 0.f;
#pragma unroll
    for (int i = 0; i < 16; ++i) s += v[i];
    float m = s * (1.0f / 16.0f);
    float sq = 0.f;
#pragma unroll
    for (int i = 0; i < 16; ++i) { float d = v[i] - m; sq += d * d; }
    float rs = rsqrtf(sq * (1.0f / 16.0f) + EPSV);
    if (!sel) {
        short* op = kout + (size_t)h * (NR * HDIM) + (size_t)nr * HDIM;
#pragma unroll
        for (int i = 0; i < 16; ++i)
            op[i] = f2b(((v[i] - m) * rs * g[i] + b[i]) * QK_SCALE);
    } else {
        short* op = vout + (size_t)h * (HDIM * NR) + nr;
#pragma unroll
        for (int i = 0; i < 16; ++i)
            op[(size_t)i * NR] = f2b((v[i] - m) * rs * g[i] + b[i]);
    }
}

// ---------------- global attention v6: MFMA flash, wave-private P in LDS -----------
// grid (128, 8); block 256 = 4 waves; wave w handles 16 q-rows of a 64-q block.
// Frag conventions (same as mgemm, verified): A row=l&15 k=(l>>4)*8..+7;
// C col=l&15, row=(l>>4)*4+reg. HD=16 zero-padded to K=32.
__global__ __launch_bounds__(256) void gattn_k(const short* __restrict__ qkv,
                                               const short* __restrict__ kb,   // [8][1024][16] *0.25
                                               const short* __restrict__ vt,   // [8][16][1024]
                                               short* __restrict__ ob) {
    __shared__ short plds[4][2048];     // per-wave P tile [16 q][128 keys] bf16, swizzled
    int t = threadIdx.x;
    int w = t >> 6, l = t & 63;
    int h = blockIdx.y;
    int lr = l & 15, lq = l >> 4;
    int q0 = blockIdx.x * 64 + w * 16;

    short8 qf = short8{0, 0, 0, 0, 0, 0, 0, 0};
    if (lq < 2)
        qf = *(const short8*)(qkv + (size_t)(q0 + lr) * 384 + h * HDIM + lq * 8);

    const short* kh = kb + (size_t)h * (NR * HDIM);
    const short* vh = vt + (size_t)h * (HDIM * NR);
    short* pw = &plds[w][0];

    const f32x4 zz = {0.f, 0.f, 0.f, 0.f};
    f32x4 oacc = {0.f, 0.f, 0.f, 0.f};
    float rs0 = 0.f, rs1 = 0.f, rs2 = 0.f, rs3 = 0.f;

    for (int c = 0; c < 8; ++c) {
        int kbase = c * 128;
        f32x4 s[8];
#pragma unroll
        for (int nf = 0; nf < 8; ++nf) {
            short8 kf = short8{0, 0, 0, 0, 0, 0, 0, 0};
            if (lq < 2)
                kf = *(const short8*)(kh + (size_t)(kbase + nf * 16 + lr) * HDIM + lq * 8);
            s[nf] = __builtin_amdgcn_mfma_f32_16x16x32_bf16(qf, kf, zz, 0, 0, 0);
        }
#pragma unroll
        for (int nf = 0; nf < 8; ++nf) {
            int key = nf * 16 + lr;
            float p0 = __expf(s[nf][0]);
            float p1 = __expf(s[nf][1]);
            float p2 = __expf(s[nf][2]);
            float p3 = __expf(s[nf][3]);
            rs0 += p0; rs1 += p1; rs2 += p2; rs3 += p3;
            int q_ = lq * 4;
            pw[((q_ + 0) * 128 + key) ^ (((q_ + 0) & 7) << 3)] = f2b(p0);
            pw[((q_ + 1) * 128 + key) ^ (((q_ + 1) & 7) << 3)] = f2b(p1);
            pw[((q_ + 2) * 128 + key) ^ (((q_ + 2) & 7) << 3)] = f2b(p2);
            pw[((q_ + 3) * 128 + key) ^ (((q_ + 3) & 7) << 3)] = f2b(p3);
        }
#pragma unroll
        for (int ks = 0; ks < 4; ++ks) {
            short8 pf = *(const short8*)&pw[(lr * 128 + ks * 32 + lq * 8) ^ ((lr & 7) << 3)];
            short8 vf = *(const short8*)(vh + (size_t)lr * NR + kbase + ks * 32 + lq * 8);
            oacc = __builtin_amdgcn_mfma_f32_16x16x32_bf16(pf, vf, oacc, 0, 0, 0);
        }
    }
    // complete row sums across the 16 key-phases (lanes sharing lq)
#pragma unroll
    for (int off = 1; off <= 8; off <<= 1) {
        rs0 += __shfl_xor(rs0, off);
        rs1 += __shfl_xor(rs1, off);
        rs2 += __shfl_xor(rs2, off);
        rs3 += __shfl_xor(rs3, off);
    }
    size_t base_o = (size_t)(q0 + lq * 4) * C_DIM + h * HDIM + lr;
    ob[base_o]             = f2b(oacc[0] / rs0);
    ob[base_o + C_DIM]     = f2b(oacc[1] / rs1);
    ob[base_o + 2 * C_DIM] = f2b(oacc[2] / rs2);
    ob[base_o + 3 * C_DIM] = f2b(oacc[3] / rs3);
}

// ---------------- final gate: out(C,N) = x * sigmoid(loc + glo) ----------------
__global__ __launch_bounds__(256) void gate_k(const float* __restrict__ x,
                                              const float* __restrict__ lf, const float* __restrict__ gf,
                                              float* __restrict__ out) {
    __shared__ float tile[32][33];
    int n0 = blockIdx.x * 32, c0 = blockIdx.y * 32;
    int tx = threadIdx.x, ty = threadIdx.y;
#pragma unroll
    for (int k = 0; k < 4; ++k) {
        int n = n0 + ty + k * 8, c = c0 + tx;
        tile[ty + k * 8][tx] = lf[(size_t)n * C_DIM + c] + gf[(size_t)n * C_DIM + c];
    }
    __syncthreads();
#pragma unroll
    for (int k = 0; k < 4; ++k) {
        int c = c0 + ty + k * 8, n = n0 + tx;
        float z = tile[tx][ty + k * 8];
        float sg = 1.0f / (1.0f + __expf(-z));
        out[(size_t)c * N_TOK + n] = x[(size_t)c * N_TOK + n] * sg;
    }
}

extern "C" void kernel_launch(void* const* d_in, const int* in_sizes, int n_in,
                              void* d_out, int out_size, void* d_ws, size_t ws_size,
                              hipStream_t stream) {
    const float* x        = (const float*)d_in[0];
    const float* l_n1_g   = (const float*)d_in[1];
    const float* l_n1_b   = (const float*)d_in[2];
    const float* l_qkv_w  = (const float*)d_in[3];
    const float* l_proj_w = (const float*)d_in[4];
    const float* l_proj_b = (const float*)d_in[5];
    const float* l_n2_g   = (const float*)d_in[6];
    const float* l_n2_b   = (const float*)d_in[7];
    const float* l_fc1_w  = (const float*)d_in[8];
    const float* l_fc1_b  = (const float*)d_in[9];
    const float* l_fc2_w  = (const float*)d_in[10];
    const float* l_fc2_b  = (const float*)d_in[11];
    const float* g_n1_g   = (const float*)d_in[12];
    const float* g_n1_b   = (const float*)d_in[13];
    const float* g_qkv_w  = (const float*)d_in[14];
    const float* g_proj_w = (const float*)d_in[15];
    const float* g_proj_b = (const float*)d_in[16];
    const float* g_n2_g   = (const float*)d_in[17];
    const float* g_n2_b   = (const float*)d_in[18];
    const float* g_fc1_w  = (const float*)d_in[19];
    const float* g_fc1_b  = (const float*)d_in[20];
    const float* g_fc2_w  = (const float*)d_in[21];
    const float* g_fc2_b  = (const float*)d_in[22];
    const float* g_ke_w   = (const float*)d_in[23];
    const float* g_ve_w   = (const float*)d_in[24];
    const float* g_nk_g   = (const float*)d_in[25];
    const float* g_nk_b   = (const float*)d_in[26];
    const float* g_nv_g   = (const float*)d_in[27];
    const float* g_nv_b   = (const float*)d_in[28];
    float* out = (float*)d_out;

    char* base = (char*)d_ws;
    float* xt     = (float*)(base);                        // 0-4 MB
    float* t1_l   = (float*)(base + (4ull  << 20));        // 4-8 MB
    float* t1_g   = (float*)(base + (8ull  << 20));        // 8-12 MB
    short* yA16   = (short*)(base + (12ull << 20));        // 12-14 MB (later t2_l)
    short* yG16   = (short*)(base + (14ull << 20));        // 14-16 MB (later t2_g)
    short* t2_l   = yA16;
    short* t2_g   = yG16;
    float* locfin = (float*)(base + (12ull << 20));        // 12-16 MB (after fc1)
    short* obuf_l = (short*)(base + (16ull << 20));        // 16-18 MB
    short* obuf_g = (short*)(base + (18ull << 20));        // 18-20 MB
    float* glofin = (float*)(base + (16ull << 20));        // 16-20 MB (after proj)
    short* qkv_l  = (short*)(base + (20ull << 20));        // 20-26 MB
    short* qkv_g  = (short*)(base + (26ull << 20));        // 26-32 MB
    short* h1_l   = (short*)(base + (32ull << 20));        // 32-40 MB
    float* kpart  = (float*)(base + (32ull << 20));        // 32-34 MB (pre-fc1)
    float* vpart  = (float*)(base + (34ull << 20));        // 34-36 MB (pre-fc1)
    short* h1_g   = (short*)(base + (40ull << 20));        // 40-48 MB
    short* kg16   = (short*)(base + (40ull << 20));        // 40-42 MB (pre-fc1)
    short* vg16   = (short*)(base + (42ull << 20));        // 42-44 MB (pre-fc1)
    short* kb16   = (short*)(base + (48ull << 20));        // 48-48.25 MB [8][1024][16]
    short* vt16   = (short*)(base + (48ull << 20) + (512ull << 10)); // [8][16][1024]
    short* wts    = (short*)(base + (49ull << 20));        // ~1.3 MB

    const int L_QKV = 0,      L_PROJ = 49152, L_FC1 = 65536,  L_FC2 = 131072;
    const int G_QKV = 196608, G_PROJ = 245760, G_FC1 = 262144, G_FC2 = 327680;
    const int G_KE  = 393216, G_VE   = 524288;

    CvtArgs ca;
    ca.d[0] = {l_qkv_w,  wts + L_QKV,  49152, 0};
    ca.d[1] = {l_proj_w, wts + L_PROJ, 16384, 0};
    ca.d[2] = {l_fc1_w,  wts + L_FC1,  65536, 0};
    ca.d[3] = {l_fc2_w,  wts + L_FC2,  65536, 0};
    ca.d[4] = {g_qkv_w,  wts + G_QKV,  49152, 0};
    ca.d[5] = {g_proj_w, wts + G_PROJ, 16384, 0};
    ca.d[6] = {g_fc1_w,  wts + G_FC1,  65536, 0};
    ca.d[7] = {g_fc2_w,  wts + G_FC2,  65536, 0};
    ca.d[8] = {g_ke_w,   wts + G_KE,  131072, 0};
    ca.d[9] = {g_ve_w,   wts + G_VE,  131072, 0};

    // 1-3: preamble
    cvtw_k<<<dim3(32, 10), 256, 0, stream>>>(ca);
    transpose_k<<<dim3(256, 4), dim3(32, 8), 0, stream>>>(x, xt);
    ln_token_k<<<2048, 256, 0, stream>>>(xt, l_n1_g, l_n1_b, yA16, g_n1_g, g_n1_b, yG16);

    // 4: both qkv GEMMs in one launch
    MArgs a_qkv = {{yA16, yG16}, {wts + L_QKV, wts + G_QKV}, {nullptr, nullptr}, {nullptr, nullptr}, {qkv_l, qkv_g}};
    mgemm_k<0><<<dim3(64, 3, 2), 256, 0, stream>>>(a_qkv, N_TOK, 384, 128, 0);

    // 5-6: local attention; global gather
    local_attn_k<<<256, dim3(32, 8), 0, stream>>>(qkv_l, obuf_l);
    gather_k<<<4096, 256, 0, stream>>>(qkv_g, kg16, vg16);

    // 7: both conv reductions, split-K x4, one launch
    MArgs a_cv = {{kg16, vg16}, {wts + G_KE, wts + G_VE}, {nullptr, nullptr}, {nullptr, nullptr}, {kpart, vpart}};
    mgemm_k<3><<<dim3(8, 1, 8), 256, 0, stream>>>(a_cv, NR, 128, 1024, 256);

    // 8: head-LN for K and V -> bf16 K (scaled) and bf16 V^T
    ln_head_sum_k<<<64, 256, 0, stream>>>(kpart, vpart, g_nk_g, g_nk_b, g_nv_g, g_nv_b, kb16, vt16);

    // 9: global attention (MFMA flash)
    gattn_k<<<dim3(128, 8), 256, 0, stream>>>(qkv_g, kb16, vt16, obuf_g);

    // 10: both proj GEMMs (+bias+residual)
    MArgs a_pj = {{obuf_l, obuf_g}, {wts + L_PROJ, wts + G_PROJ}, {l_proj_b, g_proj_b}, {xt, xt}, {t1_l, t1_g}};
    mgemm_k<1><<<dim3(64, 1, 2), 256, 0, stream>>>(a_pj, N_TOK, 128, 128, 0);

    // 11: both second LNs
    ln2_pair_k<<<4096, 256, 0, stream>>>(t1_l, l_n2_g, l_n2_b, t2_l, t1_g, g_n2_g, g_n2_b, t2_g);

    // 12: both fc1 GEMMs (+bias+gelu)
    MArgs a_f1 = {{t2_l, t2_g}, {wts + L_FC1, wts + G_FC1}, {l_fc1_b, g_fc1_b}, {nullptr, nullptr}, {h1_l, h1_g}};
    mgemm_k<2><<<dim3(64, 4, 2), 256, 0, stream>>>(a_f1, N_TOK, 512, 128, 0);

    // 13: both fc2 GEMMs (+bias+residual)
    MArgs a_f2 = {{h1_l, h1_g}, {wts + L_FC2, wts + G_FC2}, {l_fc2_b, g_fc2_b}, {t1_l, t1_g}, {locfin, glofin}};
    mgemm_k<1><<<dim3(64, 1, 2), 256, 0, stream>>>(a_f2, N_TOK, 128, 512, 0);

    // 14: gate
    gate_k<<<dim3(256, 4), dim3(32, 8), 0, stream>>>(x, locfin, glofin, out);
}